// Round 11
// baseline (211.283 us; speedup 1.0000x reference)
//
#include <hip/hip_runtime.h>

// Problem constants
#define BB   32
#define NN   512
#define SS   64
#define TPB  1024        // 16 waves; one block = one batch
#define NW   16          // waves per block; wave owns 32 nodes
#define P    16          // Chebyshev order
#define YMAX 0.8f        // |y| <= ~0.52 < YMAX
#define PI_F 3.14159265358979f

__device__ __forceinline__ float rcp_fast(float x) { return __builtin_amdgcn_rcpf(x); }

// One-time transpose gin[b][n][s] -> gt[b][s][n]
__global__ void __launch_bounds__(512)
transpose_gin(const float* __restrict__ gin, float* __restrict__ gt) {
    __shared__ float tile[64][65];
    const int b  = blockIdx.x >> 3;
    const int n0 = (blockIdx.x & 7) << 6;
    const int c  = threadIdx.x & 63;
    const int r  = threadIdx.x >> 6;
#pragma unroll
    for (int j = 0; j < 8; ++j) {
        int nl = r * 8 + j;
        tile[nl][c] = gin[b * NN * SS + (n0 + nl) * SS + c];
    }
    __syncthreads();
#pragma unroll
    for (int j = 0; j < 8; ++j) {
        int s = r * 8 + j;
        gt[b * SS * NN + s * NN + n0 + c] = tile[c][s];
    }
}

// One block per batch, barrier-free scan loop.
// s[n] = sum_p c_p[n] * M_p ;  c_p = Cheb coeffs of G_n(y)=sum_s tanh(H+y)
// (step-invariant, registers); M_p = sum_k v_k T_p(y_k/YMAX) (wave 0, per step).
// Sync: LDS cnt (16 producer arrivals) -> wave0 moments -> LDS flag -> all.
__global__ void __launch_bounds__(TPB)
spatial_attn_kernel(const float* __restrict__ gin,    // [B,N,S] fallback
                    const float* __restrict__ gt,     // [B,S,N] transposed
                    int use_t,
                    const float* __restrict__ hid,    // [B,S,N]
                    const float* __restrict__ v,      // [S]
                    const float* __restrict__ attn0,  // [B,N]
                    const float* __restrict__ W,      // [N,S]
                    const float* __restrict__ bias,   // [S]
                    float* __restrict__ out)          // [S,B,N]
{
    const int b     = blockIdx.x;
    const int t     = threadIdx.x;
    const int lane  = t & 63;
    const int w     = t >> 6;            // wave 0..15
    const int ln    = lane & 31;
    const int n_own = w * 32 + ln;       // valid for lane<32

    __shared__ float x_lds[NN];
    __shared__ float yred[NW][SS];       // unnormalized GEMV partials
    __shared__ float msA[NW], ssA[NW];   // per-wave softmax partials
    __shared__ float momt[SS][P + 1];    // moment staging (wave 0)
    __shared__ float mco[P + NW];        // [0..15]=M_p, [16..31]=outscl[w]
    __shared__ float ctab[P * P];
    __shared__ float gscr[P][NN];        // prologue scratch / c redistribution
    __shared__ unsigned int cntA, flagA;

    if (t == 0) { cntA = 0u; flagA = 0u; }
    if (t < NW) { msA[t] = 0.f; ssA[t] = 1.0f / NW; }   // => scales = 1 at step 0
    if (t < P * P) {
        int p = t >> 4, i = t & 15;
        float cs = __cosf(PI_F * (i + 0.5f) * (float)p / (float)P);
        ctab[t] = cs * ((p == 0) ? (1.0f / P) : (2.0f / P));
    }
    const float vreg = v[lane];
    const float bk   = bias[lane];

    // W cache: wave w owns rows 32w..32w+31 (matches its n ownership), col=lane
    float wr[32];
#pragma unroll
    for (int j = 0; j < 32; ++j)
        wr[j] = W[(w * 32 + j) * SS + lane];

    // Chebyshev nodes u_i = tanh(YMAX*cos(pi(i+.5)/P))
    float u[P];
#pragma unroll
    for (int i = 0; i < P; ++i) {
        float yi = YMAX * __cosf(PI_F * (i + 0.5f) / (float)P);
        float e  = __expf(2.f * yi);
        u[i] = 1.f - 2.f * rcp_fast(e + 1.f);
    }

    // ---- G_n at nodes (n = t&511, half the s-range per thread-half) ----
    const int n5 = t & 511, hs = t >> 9;
    float g[P];
#pragma unroll
    for (int i = 0; i < P; ++i) g[i] = 0.f;
    for (int s = hs * 32; s < hs * 32 + 32; ++s) {
        float H  = hid[b * SS * NN + s * NN + n5];   // coalesced
        float e2 = __expf(2.f * H);
        float T  = 1.f - 2.f * rcp_fast(e2 + 1.f);
#pragma unroll
        for (int i = 0; i < P; ++i)
            g[i] += (T + u[i]) * rcp_fast(fmaf(T, u[i], 1.f));
    }
    if (hs) {
#pragma unroll
        for (int i = 0; i < P; ++i) gscr[i][n5] = g[i];
    }
    __syncthreads();
    // DCT-II -> c_p, stored back into gscr columns (column-private, no race)
    if (t < NN) {
#pragma unroll
        for (int i = 0; i < P; ++i) g[i] += gscr[i][n5];
#pragma unroll
        for (int p = 0; p < P; ++p) {
            float a = 0.f;
#pragma unroll
            for (int i = 0; i < P; ++i) a = fmaf(ctab[p * P + i], g[i], a);
            gscr[p][n5] = a;
        }
    }
    __syncthreads();

    // ---- redistribute c to owning (wave,lane); x~(0); prefetch inp(1),(2) ----
    float cc[P];
    float x_t = 0.f, inp1 = 0.f, inp2 = 0.f;
    if (lane < 32) {
#pragma unroll
        for (int p = 0; p < P; ++p) cc[p] = gscr[p][n_own];
        float i0 = use_t ? gt[(size_t)b * SS * NN + n_own]
                         : gin[(size_t)b * NN * SS + n_own * SS];
        x_t  = attn0[b * NN + n_own] * i0;
        inp1 = use_t ? gt[(size_t)b * SS * NN + NN + n_own]
                     : gin[(size_t)b * NN * SS + n_own * SS + 1];
        inp2 = use_t ? gt[(size_t)b * SS * NN + 2 * NN + n_own]
                     : gin[(size_t)b * NN * SS + n_own * SS + 2];
        x_lds[n_own] = x_t;
    }
    // GEMV partial for step 0 (intra-wave: own x rows, lgkmcnt-ordered)
    {
        float yp = 0.f;
        const float4* xv = (const float4*)&x_lds[w * 32];
#pragma unroll
        for (int j4 = 0; j4 < 8; ++j4) {
            float4 q = xv[j4];
            yp = fmaf(q.x, wr[4 * j4 + 0], yp);
            yp = fmaf(q.y, wr[4 * j4 + 1], yp);
            yp = fmaf(q.z, wr[4 * j4 + 2], yp);
            yp = fmaf(q.w, wr[4 * j4 + 3], yp);
        }
        yred[w][lane] = yp;
    }
    if (lane == 0)
        __hip_atomic_fetch_add(&cntA, 1u, __ATOMIC_RELEASE, __HIP_MEMORY_SCOPE_WORKGROUP);

    // =================== 63 steps, barrier-free ===================
    for (int tau = 0; tau < SS - 1; ++tau) {
        if (w == 0) {
            // ---- moments wave: wait 16 producers, build y_k -> M_p, outscl ----
            const unsigned int tgt = 16u * (unsigned int)(tau + 1);
            while (__hip_atomic_load(&cntA, __ATOMIC_ACQUIRE, __HIP_MEMORY_SCOPE_WORKGROUP) < tgt)
                __builtin_amdgcn_s_sleep(1);
            float mM = msA[0];
#pragma unroll
            for (int i = 1; i < 16; ++i) mM = fmaxf(mM, msA[i]);
            float e16[16], T = 0.f;
#pragma unroll
            for (int i = 0; i < 16; ++i) {
                e16[i] = __expf(msA[i] - mM);
                T = fmaf(e16[i], ssA[i], T);
            }
            float rT = rcp_fast(T);
            float acc = 0.f;
#pragma unroll
            for (int i = 0; i < 16; ++i) acc = fmaf(e16[i], yred[i][lane], acc);
            float y  = fmaf(acc, rT, bk);
            float yt = y * (1.0f / YMAX);
            yt = fminf(1.f, fmaxf(-1.f, yt));
            float t0 = 1.f, t1 = yt;
            momt[lane][0] = vreg;
            momt[lane][1] = vreg * yt;
#pragma unroll
            for (int p = 2; p < P; ++p) {
                float t2 = fmaf(2.f * yt, t1, -t0);
                momt[lane][p] = vreg * t2;
                t0 = t1; t1 = t2;
            }
            const int pp = lane >> 2, q = lane & 3;
            float a = 0.f;
#pragma unroll
            for (int j = 0; j < 16; ++j) a += momt[q + 4 * j][pp];
            a += __shfl_xor(a, 1);
            a += __shfl_xor(a, 2);
            if (q == 0) mco[pp] = a;
            if (lane < 16) mco[P + lane] = __expf(msA[lane] - mM) * rT;  // outscl
            if (lane == 0)
                __hip_atomic_store(&flagA, (unsigned int)(tau + 1),
                                   __ATOMIC_RELEASE, __HIP_MEMORY_SCOPE_WORKGROUP);
        } else {
            while (__hip_atomic_load(&flagA, __ATOMIC_ACQUIRE, __HIP_MEMORY_SCOPE_WORKGROUP)
                   < (unsigned int)(tau + 1))
                __builtin_amdgcn_s_sleep(1);
        }

        // ---- all waves: out, s'[n], softmax, x~, own GEMV partial ----
        float inp_pf = 0.f;
        if (lane < 32) {
            int nx = (tau + 3 < SS) ? tau + 3 : SS - 1;
            inp_pf = use_t ? gt[(size_t)b * SS * NN + nx * NN + n_own]
                           : gin[(size_t)b * NN * SS + n_own * SS + nx];
        }
        float Mp[P];
#pragma unroll
        for (int p = 0; p < P; ++p) Mp[p] = mco[p];
        const float scl_own = mco[P + w];
        if (lane < 32) {
            out[(size_t)tau * BB * NN + b * NN + n_own] = x_t * scl_own;
            float s = 0.f;
#pragma unroll
            for (int p = 0; p < P; ++p) s = fmaf(cc[p], Mp[p], s);
            float m = s;
#pragma unroll
            for (int off = 1; off < 32; off <<= 1)
                m = fmaxf(m, __shfl_xor(m, off));
            float e = __expf(s - m);
            float S = e;
#pragma unroll
            for (int off = 1; off < 32; off <<= 1)
                S += __shfl_xor(S, off);
            x_t = e * inp1;
            x_lds[n_own] = x_t;
            if (ln == 0) msA[w] = m;
            if (ln == 1) ssA[w] = S;
        }
        inp1 = inp2; inp2 = inp_pf;
        {
            float yp = 0.f;
            const float4* xv = (const float4*)&x_lds[w * 32];
#pragma unroll
            for (int j4 = 0; j4 < 8; ++j4) {
                float4 q = xv[j4];
                yp = fmaf(q.x, wr[4 * j4 + 0], yp);
                yp = fmaf(q.y, wr[4 * j4 + 1], yp);
                yp = fmaf(q.z, wr[4 * j4 + 2], yp);
                yp = fmaf(q.w, wr[4 * j4 + 3], yp);
            }
            yred[w][lane] = yp;
        }
        if (lane == 0)
            __hip_atomic_fetch_add(&cntA, 1u, __ATOMIC_RELEASE, __HIP_MEMORY_SCOPE_WORKGROUP);
    }

    // ---- epilogue: out[63] ----
    while (__hip_atomic_load(&cntA, __ATOMIC_ACQUIRE, __HIP_MEMORY_SCOPE_WORKGROUP) < 16u * 64u)
        __builtin_amdgcn_s_sleep(1);
    {
        float mM = msA[0];
#pragma unroll
        for (int i = 1; i < 16; ++i) mM = fmaxf(mM, msA[i]);
        float T = 0.f;
#pragma unroll
        for (int i = 0; i < 16; ++i) T = fmaf(__expf(msA[i] - mM), ssA[i], T);
        float rT = rcp_fast(T);
        if (lane < 32)
            out[(size_t)(SS - 1) * BB * NN + b * NN + n_own] =
                x_t * (__expf(msA[w] - mM) * rT);
    }
}

extern "C" void kernel_launch(void* const* d_in, const int* in_sizes, int n_in,
                              void* d_out, int out_size, void* d_ws, size_t ws_size,
                              hipStream_t stream) {
    const float* gin   = (const float*)d_in[0];
    const float* hid   = (const float*)d_in[1];
    const float* v     = (const float*)d_in[2];
    const float* attn0 = (const float*)d_in[3];
    const float* W     = (const float*)d_in[4];
    const float* bias  = (const float*)d_in[5];
    float* out = (float*)d_out;

    float* gt = (float*)d_ws;
    size_t need_t = (size_t)BB * NN * SS * 4;
    int use_t = (ws_size >= need_t) ? 1 : 0;

    if (use_t)
        transpose_gin<<<dim3(BB * 8), dim3(512), 0, stream>>>(gin, gt);
    else
        gt = (float*)gin;

    spatial_attn_kernel<<<dim3(BB), dim3(TPB), 0, stream>>>(
        gin, gt, use_t, hid, v, attn0, W, bias, out);
}